// Round 7
// baseline (205.321 us; speedup 1.0000x reference)
//
#include <hip/hip_runtime.h>
#include <hip/hip_bf16.h>

#define DEV __device__ __forceinline__

typedef __bf16 bf16x8 __attribute__((ext_vector_type(8)));
typedef float f32x4 __attribute__((ext_vector_type(4)));
typedef float f32x16 __attribute__((ext_vector_type(16)));
using u16 = unsigned short;
using u32 = unsigned int;

static constexpr int S = 2048;
static constexpr int D = 1024;
static constexpr float SCQ = 0.125f * 1.44269504088896340736f;  // 1/sqrt(64)*log2(e)

DEV u16 f2bf(float f) {  // RNE
  unsigned u = __builtin_bit_cast(unsigned, f);
  u += 0x7fffu + ((u >> 16) & 1u);
  return (u16)(u >> 16);
}
DEV u16 f2bfr(float f) {  // round-half-up (cheap)
  return (u16)((__builtin_bit_cast(u32, f) + 0x8000u) >> 16);
}
// two f32 -> packed bf16x2, round-half-up: 2 int adds + one v_perm
DEV u32 pk2(float a, float b) {
  u32 ua = __builtin_bit_cast(u32, a) + 0x8000u;
  u32 ub = __builtin_bit_cast(u32, b) + 0x8000u;
  return __builtin_amdgcn_perm(ub, ua, 0x07060302);  // {ub[31:16], ua[31:16]}
}

// ---- merged prep: x pack + W_qkv transpose + W_out transpose (one dispatch) ----
__global__ __launch_bounds__(256) void k_prep(const float* __restrict__ x, u16* __restrict__ Xb,
                                              const float* __restrict__ Wqkv, u16* __restrict__ WqkvT,
                                              const float* __restrict__ Wout, u16* __restrict__ WoutT) {
  __shared__ float t[32][33];
  const int bid = blockIdx.x;
  const int tid = threadIdx.x;
  if (bid < 4096) {  // pack x
    const int i = bid * 256 + tid;
    const float4 v = reinterpret_cast<const float4*>(x)[i];
    ushort4 o;
    o.x = f2bf(v.x); o.y = f2bf(v.y); o.z = f2bf(v.z); o.w = f2bf(v.w);
    reinterpret_cast<ushort4*>(Xb)[i] = o;
    return;
  }
  const float* in;
  u16* out;
  int R, C, bx, by;
  if (bid < 4096 + 3072) {  // W_qkv [1024][3072] -> [3072][1024]
    const int b = bid - 4096;
    in = Wqkv; out = WqkvT; R = 1024; C = 3072;
    bx = b % 96; by = b / 96;
  } else {  // W_out [1024][1024] -> transpose
    const int b = bid - 7168;
    in = Wout; out = WoutT; R = 1024; C = 1024;
    bx = b & 31; by = b >> 5;
  }
  const int tx = tid & 31, ty = tid >> 5;
  const int c0 = bx * 32, r0 = by * 32;
  for (int i = ty; i < 32; i += 8)
    t[i][tx] = in[(size_t)(r0 + i) * C + c0 + tx];
  __syncthreads();
  for (int i = ty; i < 32; i += 8)
    out[(size_t)(c0 + i) * R + r0 + tx] = f2bf(t[tx][i]);
}

// ---- 128xTN bf16 GEMM, register double-buffer prefetch ----
template <int MODE, int TN>
__global__ __launch_bounds__(256) void k_gemm(const u16* __restrict__ A, const u16* __restrict__ Bt,
                                              const float* __restrict__ bias, int M, int N, int K,
                                              u16* __restrict__ Qb, u16* __restrict__ Kb,
                                              u16* __restrict__ Vt, float* __restrict__ outF) {
  constexpr int NJ = TN / 32;
  __shared__ u16 As[128][40];
  __shared__ u16 Bs[TN][40];
  const int tid = threadIdx.x;
  const int lane = tid & 63, wave = tid >> 6;
  const int l15 = lane & 15, quad = lane >> 4;
  const int m0 = blockIdx.y * 128, n0 = blockIdx.x * TN;
  const int wm = (wave >> 1) * 64, wn = (wave & 1) * (TN / 2);
  const int row0 = tid >> 2, c0 = (tid & 3) * 8;
  const int row1 = row0 + 64;

  f32x4 acc[4][NJ];
#pragma unroll
  for (int i = 0; i < 4; i++)
#pragma unroll
    for (int j = 0; j < NJ; j++) acc[i][j] = (f32x4){0.f, 0.f, 0.f, 0.f};

  uint4 pa0 = *reinterpret_cast<const uint4*>(&A[(size_t)(m0 + row0) * K + c0]);
  uint4 pa1 = *reinterpret_cast<const uint4*>(&A[(size_t)(m0 + row1) * K + c0]);
  uint4 pb0 = *reinterpret_cast<const uint4*>(&Bt[(size_t)(n0 + row0) * K + c0]);
  uint4 pb1;
  if constexpr (TN == 128) pb1 = *reinterpret_cast<const uint4*>(&Bt[(size_t)(n0 + row1) * K + c0]);

  for (int kk = 0; kk < K; kk += 32) {
    __syncthreads();
    *reinterpret_cast<uint4*>(&As[row0][c0]) = pa0;
    *reinterpret_cast<uint4*>(&As[row1][c0]) = pa1;
    *reinterpret_cast<uint4*>(&Bs[row0 & (TN - 1)][c0]) = pb0;
    if constexpr (TN == 128) *reinterpret_cast<uint4*>(&Bs[row1][c0]) = pb1;
    __syncthreads();
    if (kk + 32 < K) {
      pa0 = *reinterpret_cast<const uint4*>(&A[(size_t)(m0 + row0) * K + kk + 32 + c0]);
      pa1 = *reinterpret_cast<const uint4*>(&A[(size_t)(m0 + row1) * K + kk + 32 + c0]);
      pb0 = *reinterpret_cast<const uint4*>(&Bt[(size_t)(n0 + row0) * K + kk + 32 + c0]);
      if constexpr (TN == 128)
        pb1 = *reinterpret_cast<const uint4*>(&Bt[(size_t)(n0 + row1) * K + kk + 32 + c0]);
    }
    bf16x8 af[4], bfv[NJ];
#pragma unroll
    for (int i = 0; i < 4; i++)
      af[i] = *reinterpret_cast<const bf16x8*>(&As[wm + i * 16 + l15][quad * 8]);
#pragma unroll
    for (int j = 0; j < NJ; j++)
      bfv[j] = *reinterpret_cast<const bf16x8*>(&Bs[wn + j * 16 + l15][quad * 8]);
#pragma unroll
    for (int i = 0; i < 4; i++)
#pragma unroll
      for (int j = 0; j < NJ; j++)
        acc[i][j] = __builtin_amdgcn_mfma_f32_16x16x32_bf16(af[i], bfv[j], acc[i][j], 0, 0, 0);
  }

  if constexpr (MODE == 0) {
    __shared__ u16 LT[64][136];
    if (n0 >= 2048) {
      const int b = m0 >> 11, sbase = m0 & 2047;
#pragma unroll
      for (int p = 0; p < 2; p++) {
        __syncthreads();
        if ((wave & 1) == p) {
#pragma unroll
          for (int j = 0; j < NJ; j++) {
            const int n = n0 + wn + j * 16 + l15;
            const float vb = bias[n];
#pragma unroll
            for (int i = 0; i < 4; i++) {
              uint2 pw;
              pw.x = pk2(acc[i][j][0] + vb, acc[i][j][1] + vb);
              pw.y = pk2(acc[i][j][2] + vb, acc[i][j][3] + vb);
              *reinterpret_cast<uint2*>(&LT[j * 16 + l15][wm + i * 16 + quad * 4]) = pw;
            }
          }
        }
        __syncthreads();
        const int h = ((n0 - 2048) >> 6) + p;
        const int bh = b * 16 + h;
        const int nl = tid >> 2, cc = (tid & 3) * 32;
        u16* dst = &Vt[((size_t)bh * 64 + nl) * S + sbase + cc];
#pragma unroll
        for (int k = 0; k < 4; k++)
          reinterpret_cast<uint4*>(dst)[k] = *reinterpret_cast<const uint4*>(&LT[nl][cc + k * 8]);
      }
    } else {
#pragma unroll
      for (int i = 0; i < 4; i++) {
#pragma unroll
        for (int j = 0; j < NJ; j++) {
#pragma unroll
          for (int r = 0; r < 4; r++) {
            const int m = m0 + wm + i * 16 + quad * 4 + r;
            const int n = n0 + wn + j * 16 + l15;
            const float v = acc[i][j][r] + bias[n];
            const int h = (n >> 6) & 15, dh = n & 63;
            const int b = m >> 11, s = m & 2047;
            const int bh = b * 16 + h;
            if (n < 1024) Qb[((size_t)bh * S + s) * 64 + dh] = f2bfr(v * SCQ);
            else          Kb[((size_t)bh * S + s) * 64 + dh] = f2bfr(v);
          }
        }
      }
    }
  } else {
#pragma unroll
    for (int i = 0; i < 4; i++)
#pragma unroll
      for (int j = 0; j < NJ; j++)
#pragma unroll
        for (int r = 0; r < 4; r++) {
          const int m = m0 + wm + i * 16 + quad * 4 + r;
          const int n = n0 + wn + j * 16 + l15;
          outF[(size_t)m * N + n] = acc[i][j][r] + bias[n];
        }
  }
}

// ---- flash attention, split-K: grid (16 q-blocks, 2 k-slices, 32 bh) ----
// fixed-max softmax -> partials combine additively. Each block: 16 key-iters.
__global__ __launch_bounds__(256, 4) void k_attn(const u16* __restrict__ Qb,
                                                 const u16* __restrict__ Kb,
                                                 const u16* __restrict__ Vt,
                                                 u16* __restrict__ Op0, u16* __restrict__ Op1,
                                                 float* __restrict__ Li) {
  __shared__ u16 Ks[64][72];     // [key][dh]
  __shared__ u16 Vs[64][72];     // [dh][key_local]
  __shared__ u16 Pl[4][32][72];  // per-wave P: [q][key_local]; reused for O epilogue
  const int bh = blockIdx.z;
  const int ks = blockIdx.y;
  const int q0 = blockIdx.x * 128;
  const int tid = threadIdx.x;
  const int lane = tid & 63, wave = tid >> 6;
  const int l31 = lane & 31, hi = lane >> 5;
  const u16* Qh = Qb + (size_t)bh * S * 64;
  const u16* Kh = Kb + (size_t)bh * S * 64;
  const u16* Vh = Vt + (size_t)bh * 64 * S;
  const int qrow = q0 + wave * 32 + l31;
  bf16x8 qf[4];  // Q (pre-scaled) as B-operand: n = lane&31 = q
#pragma unroll
  for (int f = 0; f < 4; f++)
    qf[f] = *reinterpret_cast<const bf16x8*>(&Qh[(size_t)qrow * 64 + f * 16 + hi * 8]);

  const int r0 = tid >> 3, c0 = (tid & 7) * 8;
  const int kb0 = ks * 16, kb1 = kb0 + 16;  // this slice's key-iter range

  float li = 0.f;
  f32x16 o0, o1;  // O d-tiles: d = dt*32 + (reg&3)+8*(reg>>2)+4*hi
#pragma unroll
  for (int r = 0; r < 16; r++) { o0[r] = 0.f; o1[r] = 0.f; }

  uint4 pk0 = *reinterpret_cast<const uint4*>(&Kh[(size_t)(kb0 * 64 + r0) * 64 + c0]);
  uint4 pk1 = *reinterpret_cast<const uint4*>(&Kh[(size_t)(kb0 * 64 + r0 + 32) * 64 + c0]);
  uint4 pv0 = *reinterpret_cast<const uint4*>(&Vh[(size_t)r0 * S + kb0 * 64 + c0]);
  uint4 pv1 = *reinterpret_cast<const uint4*>(&Vh[(size_t)(r0 + 32) * S + kb0 * 64 + c0]);

  for (int kb = kb0; kb < kb1; kb++) {
    __syncthreads();
    *reinterpret_cast<uint4*>(&Ks[r0][c0]) = pk0;
    *reinterpret_cast<uint4*>(&Ks[r0 + 32][c0]) = pk1;
    *reinterpret_cast<uint4*>(&Vs[r0][c0]) = pv0;
    *reinterpret_cast<uint4*>(&Vs[r0 + 32][c0]) = pv1;
    __syncthreads();
    if (kb + 1 < kb1) {
      const u16* Kn = Kh + (size_t)(kb + 1) * 64 * 64;
      pk0 = *reinterpret_cast<const uint4*>(&Kn[(size_t)r0 * 64 + c0]);
      pk1 = *reinterpret_cast<const uint4*>(&Kn[(size_t)(r0 + 32) * 64 + c0]);
      pv0 = *reinterpret_cast<const uint4*>(&Vh[(size_t)r0 * S + (kb + 1) * 64 + c0]);
      pv1 = *reinterpret_cast<const uint4*>(&Vh[(size_t)(r0 + 32) * S + (kb + 1) * 64 + c0]);
    }
    // QK^T: 2 key-tiles x 4 k-steps (log2-domain scores)
    f32x16 z[2];
#pragma unroll
    for (int kt = 0; kt < 2; kt++) {
#pragma unroll
      for (int r = 0; r < 16; r++) z[kt][r] = 0.f;
#pragma unroll
      for (int f = 0; f < 4; f++) {
        const bf16x8 a = *reinterpret_cast<const bf16x8*>(&Ks[kt * 32 + l31][f * 16 + hi * 8]);
        z[kt] = __builtin_amdgcn_mfma_f32_32x32x16_bf16(a, qf[f], z[kt], 0, 0, 0);
      }
    }
    float s0 = 0.f, s1 = 0.f, s2 = 0.f, s3 = 0.f;
#pragma unroll
    for (int kt = 0; kt < 2; kt++)
#pragma unroll
      for (int r = 0; r < 16; r++) {
        const float p = __builtin_amdgcn_exp2f(z[kt][r]);
        z[kt][r] = p;
        if ((r & 3) == 0) s0 += p; else if ((r & 3) == 1) s1 += p;
        else if ((r & 3) == 2) s2 += p; else s3 += p;
      }
    li += (s0 + s1) + (s2 + s3);
#pragma unroll
    for (int kt = 0; kt < 2; kt++)
#pragma unroll
      for (int g = 0; g < 4; g++) {
        uint2 pw;
        pw.x = pk2(z[kt][g * 4 + 0], z[kt][g * 4 + 1]);
        pw.y = pk2(z[kt][g * 4 + 2], z[kt][g * 4 + 3]);
        *reinterpret_cast<uint2*>(&Pl[wave][l31][kt * 32 + g * 8 + hi * 4]) = pw;
      }
#pragma unroll
    for (int f = 0; f < 4; f++) {
      const bf16x8 bp = *reinterpret_cast<const bf16x8*>(&Pl[wave][l31][f * 16 + hi * 8]);
      const bf16x8 av0 = *reinterpret_cast<const bf16x8*>(&Vs[l31][f * 16 + hi * 8]);
      const bf16x8 av1 = *reinterpret_cast<const bf16x8*>(&Vs[32 + l31][f * 16 + hi * 8]);
      o0 = __builtin_amdgcn_mfma_f32_32x32x16_bf16(av0, bp, o0, 0, 0, 0);
      o1 = __builtin_amdgcn_mfma_f32_32x32x16_bf16(av1, bp, o1, 0, 0, 0);
    }
  }
  // partial li (summed across halves), one store per q
  li += __shfl_xor(li, 32);
  if (hi == 0) Li[((size_t)ks * 32 + bh) * 2048 + qrow] = li;
  // unnormalized O partial -> Pl[q][d] -> coalesced store (attnB layout)
#pragma unroll
  for (int dt = 0; dt < 2; dt++) {
    const f32x16& od = dt ? o1 : o0;
#pragma unroll
    for (int g = 0; g < 4; g++) {
      uint2 ow;
      ow.x = pk2(od[g * 4 + 0], od[g * 4 + 1]);
      ow.y = pk2(od[g * 4 + 2], od[g * 4 + 3]);
      *reinterpret_cast<uint2*>(&Pl[wave][l31][dt * 32 + g * 8 + hi * 4]) = ow;
    }
  }
  const int b = bh >> 4, h = bh & 15;
  const int mbase = b * S + q0 + wave * 32;
  const int qr = lane >> 1, ch = (lane & 1) * 32;
  u16* Opx = ks ? Op1 : Op0;
  u16* dst = &Opx[(size_t)(mbase + qr) * D + h * 64 + ch];
#pragma unroll
  for (int c = 0; c < 4; c++)
    reinterpret_cast<uint4*>(dst)[c] = *reinterpret_cast<const uint4*>(&Pl[wave][qr][ch + c * 8]);
}

// ---- combine partials: attnB = (Op0 + Op1) / (li0 + li1) ----
__global__ __launch_bounds__(256) void k_combine(const u16* __restrict__ Op0,
                                                 const u16* __restrict__ Op1,
                                                 const float* __restrict__ Li,
                                                 u16* __restrict__ attnB) {
  const int i = blockIdx.x * 256 + threadIdx.x;  // uint2 index (4 bf16 elems)
  const int e = i * 4;
  const int m = e >> 10, n = e & 1023;
  const int b = m >> 11, s = m & 2047, h = n >> 6;
  const int li_idx = ((b << 4) + h) * 2048 + s;
  const float inv = 1.f / (Li[li_idx] + Li[65536 + li_idx]);
  const uint2 a = reinterpret_cast<const uint2*>(Op0)[i];
  const uint2 c = reinterpret_cast<const uint2*>(Op1)[i];
  const float v0 = __builtin_bit_cast(float, a.x << 16) + __builtin_bit_cast(float, c.x << 16);
  const float v1 = __builtin_bit_cast(float, a.x & 0xffff0000u) +
                   __builtin_bit_cast(float, c.x & 0xffff0000u);
  const float v2 = __builtin_bit_cast(float, a.y << 16) + __builtin_bit_cast(float, c.y << 16);
  const float v3 = __builtin_bit_cast(float, a.y & 0xffff0000u) +
                   __builtin_bit_cast(float, c.y & 0xffff0000u);
  uint2 o;
  o.x = pk2(v0 * inv, v1 * inv);
  o.y = pk2(v2 * inv, v3 * inv);
  reinterpret_cast<uint2*>(attnB)[i] = o;
}

extern "C" void kernel_launch(void* const* d_in, const int* in_sizes, int n_in,
                              void* d_out, int out_size, void* d_ws, size_t ws_size,
                              hipStream_t stream) {
  const float* x = (const float*)d_in[0];
  const float* Wqkv = (const float*)d_in[1];
  const float* bqkv = (const float*)d_in[2];
  const float* Wout = (const float*)d_in[3];
  const float* bout = (const float*)d_in[4];
  float* out = (float*)d_out;

  char* p = (char*)d_ws;
  u16* Xb = (u16*)p;    p += (size_t)4096 * 1024 * 2;  // dead after gemm<0>; reused as Op0
  u16* WqkvT = (u16*)p; p += (size_t)3072 * 1024 * 2;
  u16* WoutT = (u16*)p; p += (size_t)1024 * 1024 * 2;
  u16* Qb = (u16*)p;    p += (size_t)32 * 2048 * 64 * 2;  // [bh][s][dh], pre-scaled
  u16* Kb = (u16*)p;    p += (size_t)32 * 2048 * 64 * 2;  // [bh][s][dh]
  u16* Vt = (u16*)p;    p += (size_t)32 * 64 * 2048 * 2;  // [bh][dh][s]
  u16* attnB = (u16*)p; p += (size_t)4096 * 1024 * 2;     // [4096][1024]
  u16* Op1 = (u16*)p;   p += (size_t)4096 * 1024 * 2;     // k-slice 1 partial
  float* Li = (float*)p; p += (size_t)2 * 32 * 2048 * 4;  // partial denominators
  u16* Op0 = Xb;  // overlay: slice-0 partial reuses Xb's 8.4 MB

  k_prep<<<4096 + 3072 + 1024, 256, 0, stream>>>(x, Xb, Wqkv, WqkvT, Wout, WoutT);
  k_gemm<0, 128><<<dim3(3072 / 128, 4096 / 128), 256, 0, stream>>>(
      Xb, WqkvT, bqkv, 4096, 3072, 1024, Qb, Kb, Vt, nullptr);
  k_attn<<<dim3(16, 2, 32), 256, 0, stream>>>(Qb, Kb, Vt, Op0, Op1, Li);
  k_combine<<<4096, 256, 0, stream>>>(Op0, Op1, Li, attnB);
  k_gemm<1, 64><<<dim3(1024 / 64, 4096 / 128), 256, 0, stream>>>(
      attnB, WoutT, bout, 4096, 1024, 1024, nullptr, nullptr, nullptr, out);
}